// Round 5
// baseline (385.341 us; speedup 1.0000x reference)
//
#include <hip/hip_runtime.h>
#include <hip/hip_fp16.h>
#include <math.h>

#define N_NODES 100000
#define E_EDGES 1600000
#define IN_DIM  128
#define FEAT    64
#define OUT_DIM 64
#define NBKT    391            // ceil(100000/256) buckets of 256 nodes (dst>>8)
#define CAP     6144           // per-bucket capacity (avg 4096, >30 sigma slack)
#define RNG     4096           // edges per binscatter block
#define NSCB    ((E_EDGES + RNG - 1) / RNG)   // 391
#define G1B     ((N_NODES + 255) / 256)       // 391

// ---------------- k_deg: in-degree via int atomics (runs first, unblocks gemm1) ----------------
__global__ __launch_bounds__(256) void k_deg(
    const int* __restrict__ dst, int* __restrict__ deg)
{
    int i = blockIdx.x * blockDim.x + threadIdx.x;
    int stride = gridDim.x * blockDim.x;
    for (; i < E_EDGES / 4; i += stride) {
        int4 d = ((const int4*)dst)[i];
        atomicAdd(&deg[d.x], 1);
        atomicAdd(&deg[d.y], 1);
        atomicAdd(&deg[d.z], 1);
        atomicAdd(&deg[d.w], 1);
    }
}

// ---------------- merged: binscatter (blocks 0..390) + gemm1 (blocks 391..781) ----------------
union SortGemmLDS {
    struct {
        float Ws[IN_DIM * FEAT];   // 32 KB
        float hT[16 * 260];        // 16.25 KB
    } g;
    struct {
        int hist[NBKT];
        int baseS[NBKT + 1];
        int cursor[NBKT];
        int gbase[NBKT];
        int sA[512], sB[512];
        int buf[RNG];
    } s;
};

__global__ __launch_bounds__(256, 3) void k_sort_gemm1(
    const int* __restrict__ src, const int* __restrict__ dst,
    int* __restrict__ bucket_cursor, int* __restrict__ binned,
    const float* __restrict__ h, const float* __restrict__ W1,
    const float* __restrict__ b1, const int* __restrict__ deg,
    const float* __restrict__ gate_W,
    __half* __restrict__ xs2h, float* __restrict__ aproj, float* __restrict__ bproj)
{
    __shared__ SortGemmLDS u;
    const int tid = threadIdx.x;

    if (blockIdx.x < NSCB) {
        // ---- binscatter role: block-local counting sort into 391 dst-buckets,
        // flush per-bucket runs (contiguous -> no cross-XCD line sharing).
        const int e0   = blockIdx.x * RNG;
        const int ecnt = min(RNG, E_EDGES - e0);

        for (int i = tid; i < NBKT; i += 256) u.s.hist[i] = 0;
        __syncthreads();

        int dsave[16];
#pragma unroll
        for (int k = 0; k < 16; ++k) {
            int e = e0 + k * 256 + tid;
            int d = (e < E_EDGES) ? dst[e] : -1;
            dsave[k] = d;
            if (d >= 0) atomicAdd(&u.s.hist[d >> 8], 1);
        }
        __syncthreads();

        for (int i = tid; i < 512; i += 256) u.s.sA[i] = (i < NBKT) ? u.s.hist[i] : 0;
        __syncthreads();
        int* pa = u.s.sA; int* pb = u.s.sB;
        for (int off = 1; off < 512; off <<= 1) {
            for (int i = tid; i < 512; i += 256)
                pb[i] = pa[i] + ((i >= off) ? pa[i - off] : 0);
            __syncthreads();
            int* t = pa; pa = pb; pb = t;
        }
        for (int i = tid; i < NBKT; i += 256) {
            int ex = pa[i] - u.s.hist[i];
            u.s.baseS[i]  = ex;
            u.s.cursor[i] = ex;
        }
        if (tid == 0) u.s.baseS[NBKT] = ecnt;
        __syncthreads();

#pragma unroll
        for (int k = 0; k < 16; ++k) {
            int d = dsave[k];
            if (d >= 0) {
                int e   = e0 + k * 256 + tid;
                int s   = src[e];
                int pos = atomicAdd(&u.s.cursor[d >> 8], 1);
                u.s.buf[pos] = ((d & 255) << 17) | s;   // dl:8b | src:17b
            }
        }
        __syncthreads();

        for (int t = tid; t < NBKT; t += 256) {
            int cnt = u.s.hist[t];
            u.s.gbase[t] = cnt ? atomicAdd(&bucket_cursor[t], cnt) : 0;
        }
        __syncthreads();

        for (int i = tid; i < ecnt; i += 256) {
            int lo = 0, hi = NBKT;
            while (hi - lo > 1) {
                int mid = (lo + hi) >> 1;
                if (u.s.baseS[mid] <= i) lo = mid; else hi = mid;
            }
            int off = u.s.gbase[lo] + (i - u.s.baseS[lo]);
            if (off < CAP) binned[lo * CAP + off] = u.s.buf[i];
        }
        return;
    }

    // ---- gemm1 role: xs2h = fp16(relu(h@W1+b1)*norm), aproj/bproj gate projections
    const int r0 = (blockIdx.x - NSCB) * 256;
    for (int i = tid; i < IN_DIM * FEAT / 4; i += 256)
        ((float4*)u.g.Ws)[i] = ((const float4*)W1)[i];

    const int rg = tid >> 2;     // 0..63: row group (4 rows)
    const int cg = tid & 3;      // 0..3: col group == head
    const int c0 = cg * 16;
    float acc[4][16];
#pragma unroll
    for (int i = 0; i < 4; ++i)
#pragma unroll
        for (int j = 0; j < 16; ++j) acc[i][j] = 0.f;

    const int  myrow = r0 + tid;
    const bool rok   = myrow < N_NODES;

    for (int kc = 0; kc < IN_DIM / 16; ++kc) {
        float4 f[4];
        if (rok) {
            const float4* hp = (const float4*)(h + (size_t)myrow * IN_DIM + kc * 16);
            f[0] = hp[0]; f[1] = hp[1]; f[2] = hp[2]; f[3] = hp[3];
        } else {
            f[0] = f[1] = f[2] = f[3] = make_float4(0.f, 0.f, 0.f, 0.f);
        }
        __syncthreads();
#pragma unroll
        for (int q = 0; q < 4; ++q) {
            u.g.hT[(q * 4 + 0) * 260 + tid] = f[q].x;
            u.g.hT[(q * 4 + 1) * 260 + tid] = f[q].y;
            u.g.hT[(q * 4 + 2) * 260 + tid] = f[q].z;
            u.g.hT[(q * 4 + 3) * 260 + tid] = f[q].w;
        }
        __syncthreads();
#pragma unroll
        for (int kk = 0; kk < 16; ++kk) {
            float4 a4 = *(const float4*)&u.g.hT[kk * 260 + rg * 4];
            const float* wrow = &u.g.Ws[(kc * 16 + kk) * FEAT + c0];
            float4 w0 = ((const float4*)wrow)[0];
            float4 w1 = ((const float4*)wrow)[1];
            float4 w2 = ((const float4*)wrow)[2];
            float4 w3 = ((const float4*)wrow)[3];
            const float a[4] = {a4.x, a4.y, a4.z, a4.w};
            const float w[16] = {w0.x, w0.y, w0.z, w0.w, w1.x, w1.y, w1.z, w1.w,
                                 w2.x, w2.y, w2.z, w2.w, w3.x, w3.y, w3.z, w3.w};
#pragma unroll
            for (int i = 0; i < 4; ++i)
#pragma unroll
                for (int j = 0; j < 16; ++j)
                    acc[i][j] = fmaf(a[i], w[j], acc[i][j]);
        }
    }

#pragma unroll
    for (int i = 0; i < 4; ++i) {
        int r = r0 + rg * 4 + i;
        if (r >= N_NODES) continue;
        float nr = rsqrtf(fmaxf((float)deg[r], 1.f));
        float xa = 0.f, xb = 0.f;
        alignas(16) __half hv[16];
#pragma unroll
        for (int j = 0; j < 16; ++j) {
            float v = acc[i][j] + b1[c0 + j];
            v = v > 0.f ? v : 0.f;
            xa = fmaf(v, gate_W[32 + j], xa);   // dst-side gate (raw x, pre-norm)
            xb = fmaf(v, gate_W[48 + j], xb);   // src-side gate
            hv[j] = __float2half(v * nr);
        }
        float4* xp = (float4*)(xs2h + (size_t)r * FEAT + c0);
        xp[0] = *(const float4*)&hv[0];
        xp[1] = *(const float4*)&hv[8];
        aproj[(size_t)r * 4 + cg] = xa;
        bproj[(size_t)r * 4 + cg] = xb;
    }
}

// ---------------- bucketfinal: inline scan of bucket counts + per-bucket sort ----------------
__global__ __launch_bounds__(256) void k_bucketfinal(
    const int* __restrict__ binned, const int* __restrict__ bucket_cursor,
    int* __restrict__ rowptr, int* __restrict__ src_sorted)
{
    __shared__ int sA[512], sB[512];
    __shared__ int hist[256];
    __shared__ int scn[256];
    __shared__ int cur[256];
    const int b   = blockIdx.x;
    const int tid = threadIdx.x;

    // scan 391 bucket counts locally -> eb (removes the standalone binscan kernel)
    for (int i = tid; i < 512; i += 256) sA[i] = (i < NBKT) ? bucket_cursor[i] : 0;
    __syncthreads();
    int* pa = sA; int* pb = sB;
    for (int off = 1; off < 512; off <<= 1) {
        for (int i = tid; i < 512; i += 256)
            pb[i] = pa[i] + ((i >= off) ? pa[i - off] : 0);
        __syncthreads();
        int* t = pa; pa = pb; pb = t;
    }
    const int cnt = bucket_cursor[b];
    const int eb  = pa[b] - cnt;        // exclusive prefix
    const int base = b * CAP;
    __syncthreads();

    hist[tid] = 0;
    __syncthreads();
    for (int i = tid; i < cnt; i += 256)
        atomicAdd(&hist[binned[base + i] >> 17], 1);
    __syncthreads();

    int v = hist[tid];
    scn[tid] = v;
    __syncthreads();
    for (int off = 1; off < 256; off <<= 1) {
        int add = (tid >= off) ? scn[tid - off] : 0;
        __syncthreads();
        scn[tid] += add;
        __syncthreads();
    }
    int ex = scn[tid] - v;
    cur[tid] = ex;
    int n = b * 256 + tid;
    if (n < N_NODES) rowptr[n] = eb + ex;
    if (b == 0 && tid == 0) rowptr[N_NODES] = E_EDGES;
    __syncthreads();

    for (int i = tid; i < cnt; i += 256) {
        int p   = binned[base + i];
        int dl  = p >> 17;
        int pos = atomicAdd(&cur[dl], 1);
        src_sorted[eb + pos] = p & 0x1FFFF;
    }
}

// ---------------- aggregate: 2 edges per wave (32 lanes x half2 each) ----------------
__global__ __launch_bounds__(256) void k_aggregate(
    const __half2* __restrict__ xs2h2, const float* __restrict__ aproj,
    const float* __restrict__ bproj, const int* __restrict__ rowptr,
    const int* __restrict__ src_sorted, const float* __restrict__ gate_b,
    float* __restrict__ v_out)
{
    const int tid    = threadIdx.x;
    const int lane   = tid & 63;
    const int half   = lane >> 5;        // which edge of the pair
    const int l32    = lane & 31;        // feat pair index: feats {2*l32, 2*l32+1}
    const int head   = l32 >> 3;         // pairs never straddle heads
    const int wave   = blockIdx.x * 4 + (tid >> 6);
    const int nwaves = gridDim.x * 4;
    const float gb   = gate_b[1];

    for (int n = wave; n < N_NODES; n += nwaves) {
        int beg = rowptr[n];
        int end = rowptr[n + 1];
        int cnt = end - beg;
        float a_d = aproj[(size_t)n * 4 + head] + gb;
        float2 acc = make_float2(0.f, 0.f);
        if (cnt > 0) {
            int  last = end - 1;
            int  je   = beg + half;
            bool ok   = je <= last;
            int  s    = src_sorted[ok ? je : last];
            __half2 xr = xs2h2[(size_t)s * 32 + l32];
            float   bh = bproj[(size_t)s * 4 + head];
            for (int j = beg; j < end; j += 2) {
                // prefetch next pair
                int  jn  = j + 2 + half;
                bool okn = jn < end;
                int  sn  = src_sorted[okn ? jn : last];
                __half2 xrn = xs2h2[(size_t)sn * 32 + l32];
                float   bhn = bproj[(size_t)sn * 4 + head];
                // current pair: tanh(p) = 1 - 2/(exp2(2*log2e*p)+1)
                float2 xv = __half22float2(xr);
                float  e  = __builtin_amdgcn_exp2f(2.8853900817779268f * (a_d + bh));
                float  t  = 1.f - 2.f * __builtin_amdgcn_rcpf(e + 1.f);
                t = ok ? t : 0.f;
                acc.x = fmaf(t, xv.x, acc.x);
                acc.y = fmaf(t, xv.y, acc.y);
                ok = okn; s = sn; xr = xrn; bh = bhn;
            }
        }
        // combine the two halves (both halves end with identical acc)
        acc.x += __shfl_xor(acc.x, 32, 64);
        acc.y += __shfl_xor(acc.y, 32, 64);
        float dg = fmaxf((float)cnt, 1.f);
        float nd = rsqrtf(dg);            // norm[n]
        float sd = dg * nd;               // sqrt(deg) = 1/norm
        if (half == 0) {
            float2 xn = __half22float2(xs2h2[(size_t)n * 32 + l32]);
            float2 v;
            v.x = fmaf(0.5f * sd, xn.x, acc.x * nd);
            v.y = fmaf(0.5f * sd, xn.y, acc.y * nd);
            ((float2*)v_out)[(size_t)n * 32 + l32] = v;
        }
    }
}

// ---------------- gemm2 in-place on d_out: out = v @ W2 + b2 ----------------
__global__ __launch_bounds__(256, 3) void k_gemm2(
    float* __restrict__ v, const float* __restrict__ W2, const float* __restrict__ b2)
{
    __shared__ float Ws[FEAT * OUT_DIM];  // 16 KB
    __shared__ float vT[16 * 260];        // 16.25 KB
    const int tid = threadIdx.x;
    const int r0  = blockIdx.x * 256;

    for (int i = tid; i < FEAT * OUT_DIM / 4; i += 256)
        ((float4*)Ws)[i] = ((const float4*)W2)[i];

    const int rg = tid >> 2;
    const int cg = tid & 3;
    const int c0 = cg * 16;
    float acc[4][16];
#pragma unroll
    for (int i = 0; i < 4; ++i)
#pragma unroll
        for (int j = 0; j < 16; ++j) acc[i][j] = 0.f;

    const int  myrow = r0 + tid;
    const bool rok   = myrow < N_NODES;

    for (int kc = 0; kc < FEAT / 16; ++kc) {
        float4 f[4];
        if (rok) {
            const float4* vp = (const float4*)(v + (size_t)myrow * FEAT + kc * 16);
            f[0] = vp[0]; f[1] = vp[1]; f[2] = vp[2]; f[3] = vp[3];
        } else {
            f[0] = f[1] = f[2] = f[3] = make_float4(0.f, 0.f, 0.f, 0.f);
        }
        __syncthreads();
#pragma unroll
        for (int q = 0; q < 4; ++q) {
            vT[(q * 4 + 0) * 260 + tid] = f[q].x;
            vT[(q * 4 + 1) * 260 + tid] = f[q].y;
            vT[(q * 4 + 2) * 260 + tid] = f[q].z;
            vT[(q * 4 + 3) * 260 + tid] = f[q].w;
        }
        __syncthreads();
#pragma unroll
        for (int kk = 0; kk < 16; ++kk) {
            float4 a4 = *(const float4*)&vT[kk * 260 + rg * 4];
            const float* wrow = &Ws[(kc * 16 + kk) * OUT_DIM + c0];
            float4 w0 = ((const float4*)wrow)[0];
            float4 w1 = ((const float4*)wrow)[1];
            float4 w2 = ((const float4*)wrow)[2];
            float4 w3 = ((const float4*)wrow)[3];
            const float a[4] = {a4.x, a4.y, a4.z, a4.w};
            const float w[16] = {w0.x, w0.y, w0.z, w0.w, w1.x, w1.y, w1.z, w1.w,
                                 w2.x, w2.y, w2.z, w2.w, w3.x, w3.y, w3.z, w3.w};
#pragma unroll
            for (int i = 0; i < 4; ++i)
#pragma unroll
                for (int j = 0; j < 16; ++j)
                    acc[i][j] = fmaf(a[i], w[j], acc[i][j]);
        }
    }

#pragma unroll
    for (int i = 0; i < 4; ++i) {
        int r = r0 + rg * 4 + i;
        if (r >= N_NODES) continue;
        float* op = &v[(size_t)r * OUT_DIM + c0];
#pragma unroll
        for (int q = 0; q < 4; ++q) {
            float4 o = make_float4(acc[i][q*4]   + b2[c0 + q*4],
                                   acc[i][q*4+1] + b2[c0 + q*4 + 1],
                                   acc[i][q*4+2] + b2[c0 + q*4 + 2],
                                   acc[i][q*4+3] + b2[c0 + q*4 + 3]);
            ((float4*)op)[q] = o;
        }
    }
}

extern "C" void kernel_launch(void* const* d_in, const int* in_sizes, int n_in,
                              void* d_out, int out_size, void* d_ws, size_t ws_size,
                              hipStream_t stream)
{
    const float* h   = (const float*)d_in[0];
    const int*   src = (const int*)d_in[1];
    const int*   dst = (const int*)d_in[2];
    const float* W1  = (const float*)d_in[3];
    const float* b1  = (const float*)d_in[4];
    const float* W2  = (const float*)d_in[5];
    const float* b2  = (const float*)d_in[6];
    const float* gW  = (const float*)d_in[7];
    const float* gb  = (const float*)d_in[8];
    float* out = (float*)d_out;

    // ws: binned[NBKT*CAP] | src_sorted[E] | rowptr[N+1] | deg[N] | bucket_cursor[NBKT]
    //     | aproj[N*4] f32 | bproj[N*4] f32 | xs2h[N*64] f16
    int* binned        = (int*)d_ws;
    int* src_sorted    = binned + (size_t)NBKT * CAP;
    int* rowptr        = src_sorted + E_EDGES;
    int* deg           = rowptr + (N_NODES + 1);
    int* bucket_cursor = deg + N_NODES;
    float* aproj       = (float*)(bucket_cursor + NBKT);
    float* bproj       = aproj + (size_t)N_NODES * 4;
    __half* xs2h       = (__half*)(bproj + (size_t)N_NODES * 4);

    // deg + bucket_cursor are adjacent: one memset
    hipMemsetAsync(deg, 0, (N_NODES + NBKT) * sizeof(int), stream);

    k_deg       <<<1024, 256, 0, stream>>>(dst, deg);
    k_sort_gemm1<<<NSCB + G1B, 256, 0, stream>>>(src, dst, bucket_cursor, binned,
                                                 h, W1, b1, deg, gW, xs2h, aproj, bproj);
    k_bucketfinal<<<NBKT, 256, 0, stream>>>(binned, bucket_cursor, rowptr, src_sorted);
    k_aggregate <<<2048, 256, 0, stream>>>((const __half2*)xs2h, aproj, bproj,
                                           rowptr, src_sorted, gb, out);
    k_gemm2     <<<G1B, 256, 0, stream>>>(out, W2, b2);
}

// Round 6
// 305.944 us; speedup vs baseline: 1.2595x; 1.2595x over previous
//
#include <hip/hip_runtime.h>
#include <hip/hip_fp16.h>
#include <math.h>

#define N_NODES 100000
#define E_EDGES 1600000
#define IN_DIM  128
#define FEAT    64
#define OUT_DIM 64
#define NBKT    391            // ceil(100000/256) buckets of 256 nodes (dst>>8)
#define CAP     6144           // per-bucket capacity (avg 4096, >30 sigma slack)
#define RNG     4096           // edges per binscatter block
#define NSCB    ((E_EDGES + RNG - 1) / RNG)   // 391
#define G1B     ((N_NODES + 255) / 256)       // 391

// ---------------- binscatter: block-local counting sort into 391 dst-buckets ----------------
// Flushes per-bucket RUNS (contiguous) to global binned[] -> no cross-XCD line sharing.
// bkt[] u16 sidecar replaces the old per-element binary search in the flush.
__global__ __launch_bounds__(256) void k_binscatter(
    const int* __restrict__ src, const int* __restrict__ dst,
    int* __restrict__ bucket_cursor, int* __restrict__ binned)
{
    __shared__ int hist[NBKT];
    __shared__ int baseS[NBKT];
    __shared__ int cursor[NBKT];
    __shared__ int gbase[NBKT];          // after reserve: gbase[b] - baseS[b]
    __shared__ int sA[512], sB[512];
    __shared__ int buf[RNG];             // 16 KB
    __shared__ unsigned short bkt[RNG];  // 8 KB

    const int tid  = threadIdx.x;
    const int e0   = blockIdx.x * RNG;
    const int ecnt = min(RNG, E_EDGES - e0);

    for (int i = tid; i < NBKT; i += 256) hist[i] = 0;
    __syncthreads();

    int dsave[16];
#pragma unroll
    for (int k = 0; k < 16; ++k) {
        int e = e0 + k * 256 + tid;
        int d = (e < E_EDGES) ? dst[e] : -1;
        dsave[k] = d;
        if (d >= 0) atomicAdd(&hist[d >> 8], 1);
    }
    __syncthreads();

    // exclusive scan of hist (padded 512, double-buffered)
    for (int i = tid; i < 512; i += 256) sA[i] = (i < NBKT) ? hist[i] : 0;
    __syncthreads();
    int* pa = sA; int* pb = sB;
    for (int off = 1; off < 512; off <<= 1) {
        for (int i = tid; i < 512; i += 256)
            pb[i] = pa[i] + ((i >= off) ? pa[i - off] : 0);
        __syncthreads();
        int* t = pa; pa = pb; pb = t;
    }
    for (int i = tid; i < NBKT; i += 256) {
        int ex = pa[i] - hist[i];
        baseS[i]  = ex;
        cursor[i] = ex;
    }
    __syncthreads();

    // local scatter (bucket-major) + bucket-id sidecar
#pragma unroll
    for (int k = 0; k < 16; ++k) {
        int d = dsave[k];
        if (d >= 0) {
            int e   = e0 + k * 256 + tid;
            int s   = src[e];
            int b   = d >> 8;
            int pos = atomicAdd(&cursor[b], 1);
            buf[pos] = ((d & 255) << 17) | s;   // dl:8b | src:17b
            bkt[pos] = (unsigned short)b;
        }
    }
    __syncthreads();

    // reserve global run space; fold gbase - baseS so the flush is one add
    for (int t = tid; t < NBKT; t += 256) {
        int cnt = hist[t];
        int g   = cnt ? atomicAdd(&bucket_cursor[t], cnt) : 0;
        gbase[t] = g - baseS[t];
    }
    __syncthreads();

    // flush runs: direct addressing, no search
    for (int i = tid; i < ecnt; i += 256) {
        int b   = bkt[i];
        int off = gbase[b] + i;             // == gbase0 + (i - baseS[b])
        if (off < CAP) binned[b * CAP + off] = buf[i];
    }
}

// ---------------- bucketfinal: inline scan of bucket counts + per-bucket node sort ----------------
// Writes deg, rowptr, src_sorted. One block per 256-node bucket; the 16KB
// src_sorted window is written by exactly one block -> full-line writeback.
__global__ __launch_bounds__(256) void k_bucketfinal(
    const int* __restrict__ binned, const int* __restrict__ bucket_cursor,
    int* __restrict__ deg, int* __restrict__ rowptr, int* __restrict__ src_sorted)
{
    __shared__ int sA[512], sB[512];
    __shared__ int hist[256];
    __shared__ int scn[256];
    __shared__ int cur[256];
    const int b   = blockIdx.x;
    const int tid = threadIdx.x;

    // scan all 391 bucket counts locally -> this bucket's global edge base
    for (int i = tid; i < 512; i += 256) sA[i] = (i < NBKT) ? bucket_cursor[i] : 0;
    __syncthreads();
    int* pa = sA; int* pb = sB;
    for (int off = 1; off < 512; off <<= 1) {
        for (int i = tid; i < 512; i += 256)
            pb[i] = pa[i] + ((i >= off) ? pa[i - off] : 0);
        __syncthreads();
        int* t = pa; pa = pb; pb = t;
    }
    const int cnt  = bucket_cursor[b];
    const int eb   = pa[b] - cnt;        // exclusive prefix
    const int base = b * CAP;
    __syncthreads();

    hist[tid] = 0;
    __syncthreads();
    for (int i = tid; i < cnt; i += 256)
        atomicAdd(&hist[binned[base + i] >> 17], 1);
    __syncthreads();

    int v = hist[tid];
    scn[tid] = v;
    __syncthreads();
    for (int off = 1; off < 256; off <<= 1) {
        int add = (tid >= off) ? scn[tid - off] : 0;
        __syncthreads();
        scn[tid] += add;
        __syncthreads();
    }
    int ex = scn[tid] - v;
    cur[tid] = ex;
    int n = b * 256 + tid;
    if (n < N_NODES) {
        deg[n]    = v;
        rowptr[n] = eb + ex;
    }
    if (b == 0 && tid == 0) rowptr[N_NODES] = E_EDGES;
    __syncthreads();

    for (int i = tid; i < cnt; i += 256) {
        int p   = binned[base + i];
        int dl  = p >> 17;
        int pos = atomicAdd(&cur[dl], 1);
        src_sorted[eb + pos] = p & 0x1FFFF;
    }
}

// ---------------- gemm1: xs2h = fp16( relu(h@W1+b1)*norm ), aproj/bproj gate projections ----------------
__global__ __launch_bounds__(256, 3) void k_gemm1(
    const float* __restrict__ h, const float* __restrict__ W1,
    const float* __restrict__ b1, const int* __restrict__ deg,
    const float* __restrict__ gate_W,
    __half* __restrict__ xs2h, float* __restrict__ aproj, float* __restrict__ bproj)
{
    __shared__ float Ws[IN_DIM * FEAT];   // 32 KB
    __shared__ float hT[16 * 260];        // 16.25 KB transposed tile
    const int tid = threadIdx.x;
    const int r0  = blockIdx.x * 256;

    for (int i = tid; i < IN_DIM * FEAT / 4; i += 256)
        ((float4*)Ws)[i] = ((const float4*)W1)[i];

    const int rg = tid >> 2;     // 0..63: row group (4 rows)
    const int cg = tid & 3;      // 0..3: col group == head
    const int c0 = cg * 16;
    float acc[4][16];
#pragma unroll
    for (int i = 0; i < 4; ++i)
#pragma unroll
        for (int j = 0; j < 16; ++j) acc[i][j] = 0.f;

    const int  myrow = r0 + tid;
    const bool rok   = myrow < N_NODES;

    for (int kc = 0; kc < IN_DIM / 16; ++kc) {
        float4 f[4];
        if (rok) {
            const float4* hp = (const float4*)(h + (size_t)myrow * IN_DIM + kc * 16);
            f[0] = hp[0]; f[1] = hp[1]; f[2] = hp[2]; f[3] = hp[3];
        } else {
            f[0] = f[1] = f[2] = f[3] = make_float4(0.f, 0.f, 0.f, 0.f);
        }
        __syncthreads();
#pragma unroll
        for (int q = 0; q < 4; ++q) {
            hT[(q * 4 + 0) * 260 + tid] = f[q].x;
            hT[(q * 4 + 1) * 260 + tid] = f[q].y;
            hT[(q * 4 + 2) * 260 + tid] = f[q].z;
            hT[(q * 4 + 3) * 260 + tid] = f[q].w;
        }
        __syncthreads();
#pragma unroll
        for (int kk = 0; kk < 16; ++kk) {
            float4 a4 = *(const float4*)&hT[kk * 260 + rg * 4];
            const float* wrow = &Ws[(kc * 16 + kk) * FEAT + c0];
            float4 w0 = ((const float4*)wrow)[0];
            float4 w1 = ((const float4*)wrow)[1];
            float4 w2 = ((const float4*)wrow)[2];
            float4 w3 = ((const float4*)wrow)[3];
            const float a[4] = {a4.x, a4.y, a4.z, a4.w};
            const float w[16] = {w0.x, w0.y, w0.z, w0.w, w1.x, w1.y, w1.z, w1.w,
                                 w2.x, w2.y, w2.z, w2.w, w3.x, w3.y, w3.z, w3.w};
#pragma unroll
            for (int i = 0; i < 4; ++i)
#pragma unroll
                for (int j = 0; j < 16; ++j)
                    acc[i][j] = fmaf(a[i], w[j], acc[i][j]);
        }
    }

#pragma unroll
    for (int i = 0; i < 4; ++i) {
        int r = r0 + rg * 4 + i;
        if (r >= N_NODES) continue;
        float nr = rsqrtf(fmaxf((float)deg[r], 1.f));
        float xa = 0.f, xb = 0.f;
        alignas(16) __half hv[16];
#pragma unroll
        for (int j = 0; j < 16; ++j) {
            float v = acc[i][j] + b1[c0 + j];
            v = v > 0.f ? v : 0.f;
            xa = fmaf(v, gate_W[32 + j], xa);   // dst-side gate (raw x, pre-norm)
            xb = fmaf(v, gate_W[48 + j], xb);   // src-side gate
            hv[j] = __float2half(v * nr);
        }
        float4* xp = (float4*)(xs2h + (size_t)r * FEAT + c0);
        xp[0] = *(const float4*)&hv[0];
        xp[1] = *(const float4*)&hv[8];
        aproj[(size_t)r * 4 + cg] = xa;
        bproj[(size_t)r * 4 + cg] = xb;
    }
}

// ---------------- aggregate: 2 edges/wave, 3-deep src pipe + 2-deep feature pipe ----------------
__global__ __launch_bounds__(256) void k_aggregate(
    const __half2* __restrict__ xs2h2, const float* __restrict__ aproj,
    const float* __restrict__ bproj, const int* __restrict__ rowptr,
    const int* __restrict__ src_sorted, const float* __restrict__ gate_b,
    float* __restrict__ v_out)
{
    const int tid    = threadIdx.x;
    const int lane   = tid & 63;
    const int half   = lane >> 5;        // which edge of the pair
    const int l32    = lane & 31;        // feat pair: {2*l32, 2*l32+1}
    const int head   = l32 >> 3;         // pairs never straddle heads
    const int wave   = blockIdx.x * 4 + (tid >> 6);
    const int nwaves = gridDim.x * 4;
    const float gb   = gate_b[1];

    for (int n = wave; n < N_NODES; n += nwaves) {
        int beg = rowptr[n];
        int end = rowptr[n + 1];
        int cnt = end - beg;
        float a_d = aproj[(size_t)n * 4 + head] + gb;
        float2 acc = make_float2(0.f, 0.f);
        if (cnt > 0) {
            int last = end - 1;
            // preamble: stage0/1 fully loaded, stage2 src-only
            int  j0  = beg + half;
            int  j1  = beg + 2 + half;
            int  j2  = beg + 4 + half;
            bool ok0 = j0 < end, ok1 = j1 < end, ok2 = j2 < end;
            int  t0  = src_sorted[ok0 ? j0 : last];
            int  t1  = src_sorted[ok1 ? j1 : last];
            int  s2  = src_sorted[ok2 ? j2 : last];
            __half2 x0 = xs2h2[(size_t)t0 * 32 + l32];
            float   b0 = bproj[(size_t)t0 * 4 + head];
            __half2 x1 = xs2h2[(size_t)t1 * 32 + l32];
            float   b1 = bproj[(size_t)t1 * 4 + head];
            for (int j = beg; j < end; j += 2) {
                // issue src for j+6 (no dependency) and features for s2 (loaded 2 iters ago)
                int  j3  = j + 6 + half;
                bool ok3 = j3 < end;
                int  s3  = src_sorted[ok3 ? j3 : last];
                __half2 x2 = xs2h2[(size_t)s2 * 32 + l32];
                float   b2 = bproj[(size_t)s2 * 4 + head];
                // process stage0: tanh(p) = 1 - 2/(exp2(2*log2e*p)+1), safe at +/-inf
                float2 xv = __half22float2(x0);
                float  e  = __builtin_amdgcn_exp2f(2.8853900817779268f * (a_d + b0));
                float  t  = 1.f - 2.f * __builtin_amdgcn_rcpf(e + 1.f);
                t = ok0 ? t : 0.f;
                acc.x = fmaf(t, xv.x, acc.x);
                acc.y = fmaf(t, xv.y, acc.y);
                // shift pipeline
                ok0 = ok1; x0 = x1; b0 = b1;
                ok1 = ok2; x1 = x2; b1 = b2;
                ok2 = ok3; s2 = s3;
            }
        }
        // combine the two halves
        acc.x += __shfl_xor(acc.x, 32, 64);
        acc.y += __shfl_xor(acc.y, 32, 64);
        float dg = fmaxf((float)cnt, 1.f);
        float nd = rsqrtf(dg);            // norm[n]
        float sd = dg * nd;               // sqrt(deg) = 1/norm
        if (half == 0) {
            float2 xn = __half22float2(xs2h2[(size_t)n * 32 + l32]);
            float2 v;
            v.x = fmaf(0.5f * sd, xn.x, acc.x * nd);
            v.y = fmaf(0.5f * sd, xn.y, acc.y * nd);
            ((float2*)v_out)[(size_t)n * 32 + l32] = v;
        }
    }
}

// ---------------- gemm2 in-place on d_out: out = v @ W2 + b2 ----------------
__global__ __launch_bounds__(256, 3) void k_gemm2(
    float* __restrict__ v, const float* __restrict__ W2, const float* __restrict__ b2)
{
    __shared__ float Ws[FEAT * OUT_DIM];  // 16 KB
    __shared__ float vT[16 * 260];        // 16.25 KB
    const int tid = threadIdx.x;
    const int r0  = blockIdx.x * 256;

    for (int i = tid; i < FEAT * OUT_DIM / 4; i += 256)
        ((float4*)Ws)[i] = ((const float4*)W2)[i];

    const int rg = tid >> 2;
    const int cg = tid & 3;
    const int c0 = cg * 16;
    float acc[4][16];
#pragma unroll
    for (int i = 0; i < 4; ++i)
#pragma unroll
        for (int j = 0; j < 16; ++j) acc[i][j] = 0.f;

    const int  myrow = r0 + tid;
    const bool rok   = myrow < N_NODES;

    for (int kc = 0; kc < FEAT / 16; ++kc) {
        float4 f[4];
        if (rok) {
            const float4* vp = (const float4*)(v + (size_t)myrow * FEAT + kc * 16);
            f[0] = vp[0]; f[1] = vp[1]; f[2] = vp[2]; f[3] = vp[3];
        } else {
            f[0] = f[1] = f[2] = f[3] = make_float4(0.f, 0.f, 0.f, 0.f);
        }
        __syncthreads();
#pragma unroll
        for (int q = 0; q < 4; ++q) {
            vT[(q * 4 + 0) * 260 + tid] = f[q].x;
            vT[(q * 4 + 1) * 260 + tid] = f[q].y;
            vT[(q * 4 + 2) * 260 + tid] = f[q].z;
            vT[(q * 4 + 3) * 260 + tid] = f[q].w;
        }
        __syncthreads();
#pragma unroll
        for (int kk = 0; kk < 16; ++kk) {
            float4 a4 = *(const float4*)&vT[kk * 260 + rg * 4];
            const float* wrow = &Ws[(kc * 16 + kk) * OUT_DIM + c0];
            float4 w0 = ((const float4*)wrow)[0];
            float4 w1 = ((const float4*)wrow)[1];
            float4 w2 = ((const float4*)wrow)[2];
            float4 w3 = ((const float4*)wrow)[3];
            const float a[4] = {a4.x, a4.y, a4.z, a4.w};
            const float w[16] = {w0.x, w0.y, w0.z, w0.w, w1.x, w1.y, w1.z, w1.w,
                                 w2.x, w2.y, w2.z, w2.w, w3.x, w3.y, w3.z, w3.w};
#pragma unroll
            for (int i = 0; i < 4; ++i)
#pragma unroll
                for (int j = 0; j < 16; ++j)
                    acc[i][j] = fmaf(a[i], w[j], acc[i][j]);
        }
    }

#pragma unroll
    for (int i = 0; i < 4; ++i) {
        int r = r0 + rg * 4 + i;
        if (r >= N_NODES) continue;
        float* op = &v[(size_t)r * OUT_DIM + c0];
#pragma unroll
        for (int q = 0; q < 4; ++q) {
            float4 o = make_float4(acc[i][q*4]   + b2[c0 + q*4],
                                   acc[i][q*4+1] + b2[c0 + q*4 + 1],
                                   acc[i][q*4+2] + b2[c0 + q*4 + 2],
                                   acc[i][q*4+3] + b2[c0 + q*4 + 3]);
            ((float4*)op)[q] = o;
        }
    }
}

extern "C" void kernel_launch(void* const* d_in, const int* in_sizes, int n_in,
                              void* d_out, int out_size, void* d_ws, size_t ws_size,
                              hipStream_t stream)
{
    const float* h   = (const float*)d_in[0];
    const int*   src = (const int*)d_in[1];
    const int*   dst = (const int*)d_in[2];
    const float* W1  = (const float*)d_in[3];
    const float* b1  = (const float*)d_in[4];
    const float* W2  = (const float*)d_in[5];
    const float* b2  = (const float*)d_in[6];
    const float* gW  = (const float*)d_in[7];
    const float* gb  = (const float*)d_in[8];
    float* out = (float*)d_out;

    // ws: bucket_cursor[NBKT] | binned[NBKT*CAP] | src_sorted[E] | rowptr[N+1] | deg[N]
    //     | aproj[N*4] f32 | bproj[N*4] f32 | xs2h[N*64] f16
    int* bucket_cursor = (int*)d_ws;
    int* binned        = bucket_cursor + NBKT;
    int* src_sorted    = binned + (size_t)NBKT * CAP;
    int* rowptr        = src_sorted + E_EDGES;
    int* deg           = rowptr + (N_NODES + 1);
    float* aproj       = (float*)(deg + N_NODES);
    float* bproj       = aproj + (size_t)N_NODES * 4;
    __half* xs2h       = (__half*)(bproj + (size_t)N_NODES * 4);

    hipMemsetAsync(bucket_cursor, 0, NBKT * sizeof(int), stream);

    k_binscatter <<<NSCB, 256, 0, stream>>>(src, dst, bucket_cursor, binned);
    k_bucketfinal<<<NBKT, 256, 0, stream>>>(binned, bucket_cursor, deg, rowptr, src_sorted);
    k_gemm1      <<<G1B, 256, 0, stream>>>(h, W1, b1, deg, gW, xs2h, aproj, bproj);
    k_aggregate  <<<2048, 256, 0, stream>>>((const __half2*)xs2h, aproj, bproj,
                                            rowptr, src_sorted, gb, out);
    k_gemm2      <<<G1B, 256, 0, stream>>>(out, W2, b2);
}

// Round 7
// 267.334 us; speedup vs baseline: 1.4414x; 1.1444x over previous
//
#include <hip/hip_runtime.h>
#include <hip/hip_fp16.h>
#include <math.h>

#define N_NODES 100000
#define E_EDGES 1600000
#define IN_DIM  128
#define FEAT    64
#define OUT_DIM 64
#define NBKT    391            // ceil(100000/256) buckets of 256 nodes (dst>>8)
#define CAP     6144           // per-bucket capacity (avg 4096, >30 sigma slack)
#define RNG     4096           // edges per binscatter block
#define NSCB    ((E_EDGES + RNG - 1) / RNG)   // 391
#define G1B     ((N_NODES + 255) / 256)       // 391

typedef float vfloat2 __attribute__((ext_vector_type(2)));

// ---------------- binscatter: block-local counting sort into 391 dst-buckets ----------------
__global__ __launch_bounds__(256) void k_binscatter(
    const int* __restrict__ src, const int* __restrict__ dst,
    int* __restrict__ bucket_cursor, int* __restrict__ binned)
{
    __shared__ int hist[NBKT];
    __shared__ int baseS[NBKT];
    __shared__ int cursor[NBKT];
    __shared__ int gbase[NBKT];          // after reserve: gbase[b] - baseS[b]
    __shared__ int sA[512], sB[512];
    __shared__ int buf[RNG];             // 16 KB
    __shared__ unsigned short bkt[RNG];  // 8 KB

    const int tid  = threadIdx.x;
    const int e0   = blockIdx.x * RNG;
    const int ecnt = min(RNG, E_EDGES - e0);

    for (int i = tid; i < NBKT; i += 256) hist[i] = 0;
    __syncthreads();

    int dsave[16];
#pragma unroll
    for (int k = 0; k < 16; ++k) {
        int e = e0 + k * 256 + tid;
        int d = (e < E_EDGES) ? dst[e] : -1;
        dsave[k] = d;
        if (d >= 0) atomicAdd(&hist[d >> 8], 1);
    }
    __syncthreads();

    for (int i = tid; i < 512; i += 256) sA[i] = (i < NBKT) ? hist[i] : 0;
    __syncthreads();
    int* pa = sA; int* pb = sB;
    for (int off = 1; off < 512; off <<= 1) {
        for (int i = tid; i < 512; i += 256)
            pb[i] = pa[i] + ((i >= off) ? pa[i - off] : 0);
        __syncthreads();
        int* t = pa; pa = pb; pb = t;
    }
    for (int i = tid; i < NBKT; i += 256) {
        int ex = pa[i] - hist[i];
        baseS[i]  = ex;
        cursor[i] = ex;
    }
    __syncthreads();

#pragma unroll
    for (int k = 0; k < 16; ++k) {
        int d = dsave[k];
        if (d >= 0) {
            int e   = e0 + k * 256 + tid;
            int s   = src[e];
            int b   = d >> 8;
            int pos = atomicAdd(&cursor[b], 1);
            buf[pos] = ((d & 255) << 17) | s;   // dl:8b | src:17b
            bkt[pos] = (unsigned short)b;
        }
    }
    __syncthreads();

    for (int t = tid; t < NBKT; t += 256) {
        int cnt = hist[t];
        int g   = cnt ? atomicAdd(&bucket_cursor[t], cnt) : 0;
        gbase[t] = g - baseS[t];
    }
    __syncthreads();

    for (int i = tid; i < ecnt; i += 256) {
        int b   = bkt[i];
        int off = gbase[b] + i;
        if (off < CAP) binned[b * CAP + off] = buf[i];
    }
}

// ---------------- bucketfinal: inline scan + per-bucket node sort ----------------
__global__ __launch_bounds__(256) void k_bucketfinal(
    const int* __restrict__ binned, const int* __restrict__ bucket_cursor,
    int* __restrict__ deg, int* __restrict__ rowptr, int* __restrict__ src_sorted)
{
    __shared__ int sA[512], sB[512];
    __shared__ int hist[256];
    __shared__ int scn[256];
    __shared__ int cur[256];
    const int b   = blockIdx.x;
    const int tid = threadIdx.x;

    for (int i = tid; i < 512; i += 256) sA[i] = (i < NBKT) ? bucket_cursor[i] : 0;
    __syncthreads();
    int* pa = sA; int* pb = sB;
    for (int off = 1; off < 512; off <<= 1) {
        for (int i = tid; i < 512; i += 256)
            pb[i] = pa[i] + ((i >= off) ? pa[i - off] : 0);
        __syncthreads();
        int* t = pa; pa = pb; pb = t;
    }
    const int cnt  = bucket_cursor[b];
    const int eb   = pa[b] - cnt;
    const int base = b * CAP;
    __syncthreads();

    hist[tid] = 0;
    __syncthreads();
    for (int i = tid; i < cnt; i += 256)
        atomicAdd(&hist[binned[base + i] >> 17], 1);
    __syncthreads();

    int v = hist[tid];
    scn[tid] = v;
    __syncthreads();
    for (int off = 1; off < 256; off <<= 1) {
        int add = (tid >= off) ? scn[tid - off] : 0;
        __syncthreads();
        scn[tid] += add;
        __syncthreads();
    }
    int ex = scn[tid] - v;
    cur[tid] = ex;
    int n = b * 256 + tid;
    if (n < N_NODES) {
        deg[n]    = v;
        rowptr[n] = eb + ex;
    }
    if (b == 0 && tid == 0) rowptr[N_NODES] = E_EDGES;
    __syncthreads();

    for (int i = tid; i < cnt; i += 256) {
        int p   = binned[base + i];
        int dl  = p >> 17;
        int pos = atomicAdd(&cur[dl], 1);
        src_sorted[eb + pos] = p & 0x1FFFF;
    }
}

// ---------------- gemm1: xs2h fp16 + xq fp8 (both = relu(h@W1+b1)*norm), gate projections ----------------
__global__ __launch_bounds__(256, 3) void k_gemm1(
    const float* __restrict__ h, const float* __restrict__ W1,
    const float* __restrict__ b1, const int* __restrict__ deg,
    const float* __restrict__ gate_W,
    __half* __restrict__ xs2h, unsigned int* __restrict__ xq,
    float* __restrict__ aproj, float* __restrict__ bproj)
{
    __shared__ float Ws[IN_DIM * FEAT];   // 32 KB
    __shared__ float hT[16 * 260];        // 16.25 KB transposed tile
    const int tid = threadIdx.x;
    const int r0  = blockIdx.x * 256;

    for (int i = tid; i < IN_DIM * FEAT / 4; i += 256)
        ((float4*)Ws)[i] = ((const float4*)W1)[i];

    const int rg = tid >> 2;     // 0..63: row group (4 rows)
    const int cg = tid & 3;      // 0..3: col group == head
    const int c0 = cg * 16;
    float acc[4][16];
#pragma unroll
    for (int i = 0; i < 4; ++i)
#pragma unroll
        for (int j = 0; j < 16; ++j) acc[i][j] = 0.f;

    const int  myrow = r0 + tid;
    const bool rok   = myrow < N_NODES;

    for (int kc = 0; kc < IN_DIM / 16; ++kc) {
        float4 f[4];
        if (rok) {
            const float4* hp = (const float4*)(h + (size_t)myrow * IN_DIM + kc * 16);
            f[0] = hp[0]; f[1] = hp[1]; f[2] = hp[2]; f[3] = hp[3];
        } else {
            f[0] = f[1] = f[2] = f[3] = make_float4(0.f, 0.f, 0.f, 0.f);
        }
        __syncthreads();
#pragma unroll
        for (int q = 0; q < 4; ++q) {
            hT[(q * 4 + 0) * 260 + tid] = f[q].x;
            hT[(q * 4 + 1) * 260 + tid] = f[q].y;
            hT[(q * 4 + 2) * 260 + tid] = f[q].z;
            hT[(q * 4 + 3) * 260 + tid] = f[q].w;
        }
        __syncthreads();
#pragma unroll
        for (int kk = 0; kk < 16; ++kk) {
            float4 a4 = *(const float4*)&hT[kk * 260 + rg * 4];
            const float* wrow = &Ws[(kc * 16 + kk) * FEAT + c0];
            float4 w0 = ((const float4*)wrow)[0];
            float4 w1 = ((const float4*)wrow)[1];
            float4 w2 = ((const float4*)wrow)[2];
            float4 w3 = ((const float4*)wrow)[3];
            const float a[4] = {a4.x, a4.y, a4.z, a4.w};
            const float w[16] = {w0.x, w0.y, w0.z, w0.w, w1.x, w1.y, w1.z, w1.w,
                                 w2.x, w2.y, w2.z, w2.w, w3.x, w3.y, w3.z, w3.w};
#pragma unroll
            for (int i = 0; i < 4; ++i)
#pragma unroll
                for (int j = 0; j < 16; ++j)
                    acc[i][j] = fmaf(a[i], w[j], acc[i][j]);
        }
    }

#pragma unroll
    for (int i = 0; i < 4; ++i) {
        int r = r0 + rg * 4 + i;
        if (r >= N_NODES) continue;
        float nr = rsqrtf(fmaxf((float)deg[r], 1.f));
        float xa = 0.f, xb = 0.f;
        alignas(16) __half hv[16];
        float vs[16];
#pragma unroll
        for (int j = 0; j < 16; ++j) {
            float v = acc[i][j] + b1[c0 + j];
            v = v > 0.f ? v : 0.f;
            xa = fmaf(v, gate_W[32 + j], xa);   // dst-side gate (raw x)
            xb = fmaf(v, gate_W[48 + j], xb);   // src-side gate
            float sv = v * nr;
            vs[j] = sv;
            hv[j] = __float2half(sv);
        }
        // fp16 row (residual path)
        float4* xp = (float4*)(xs2h + (size_t)r * FEAT + c0);
        xp[0] = *(const float4*)&hv[0];
        xp[1] = *(const float4*)&hv[8];
        // fp8 row (gather path): 4 uints = 16 bytes
        unsigned int u[4];
#pragma unroll
        for (int q = 0; q < 4; ++q) {
            unsigned int t = 0;
            t = __builtin_amdgcn_cvt_pk_fp8_f32(vs[q*4+0], vs[q*4+1], t, false);
            t = __builtin_amdgcn_cvt_pk_fp8_f32(vs[q*4+2], vs[q*4+3], t, true);
            u[q] = t;
        }
        ((uint4*)xq)[(size_t)r * 4 + cg] = make_uint4(u[0], u[1], u[2], u[3]);
        aproj[(size_t)r * 4 + cg] = xa;
        bproj[(size_t)r * 4 + cg] = xb;
    }
}

// ---------------- aggregate: 4 edges/wave, fp8 gather (64 B/edge), fp16 residual ----------------
__global__ __launch_bounds__(256) void k_aggregate(
    const unsigned int* __restrict__ xq, const __half2* __restrict__ xs2h2,
    const float* __restrict__ aproj, const float* __restrict__ bproj,
    const int* __restrict__ rowptr, const int* __restrict__ src_sorted,
    const float* __restrict__ gate_b, float* __restrict__ v_out)
{
    const int tid    = threadIdx.x;
    const int lane   = tid & 63;
    const int q      = lane >> 4;        // which edge of the 4
    const int l16    = lane & 15;        // feat quad: {4*l16 .. 4*l16+3}
    const int head   = l16 >> 2;         // quads never straddle heads
    const int wave   = blockIdx.x * 4 + (tid >> 6);
    const int nwaves = gridDim.x * 4;
    const float gb   = gate_b[1];

    for (int n = wave; n < N_NODES; n += nwaves) {
        int beg = rowptr[n];
        int end = rowptr[n + 1];
        int cnt = end - beg;
        float a_d = aproj[(size_t)n * 4 + head] + gb;
        float4 acc = make_float4(0.f, 0.f, 0.f, 0.f);
        if (cnt > 0) {
            int  last = end - 1;
            int  j0   = beg + q;
            bool ok0  = j0 < end;
            int  s0   = src_sorted[ok0 ? j0 : last];
            unsigned int x0 = xq[(size_t)s0 * 16 + l16];
            float        b0 = bproj[(size_t)s0 * 4 + head];
            for (int j = beg; j < end; j += 4) {
                int  jn  = j + 4 + q;
                bool okn = jn < end;
                int  sn  = src_sorted[okn ? jn : last];
                unsigned int xn = xq[(size_t)sn * 16 + l16];
                float        bn = bproj[(size_t)sn * 4 + head];
                // decode fp8 quad + gate: tanh(p) = 1 - 2/(exp2(2*log2e*p)+1)
                vfloat2 lo = __builtin_amdgcn_cvt_pk_f32_fp8(x0, false);
                vfloat2 hi = __builtin_amdgcn_cvt_pk_f32_fp8(x0, true);
                float e = __builtin_amdgcn_exp2f(2.8853900817779268f * (a_d + b0));
                float t = 1.f - 2.f * __builtin_amdgcn_rcpf(e + 1.f);
                t = ok0 ? t : 0.f;
                acc.x = fmaf(t, lo[0], acc.x);
                acc.y = fmaf(t, lo[1], acc.y);
                acc.z = fmaf(t, hi[0], acc.z);
                acc.w = fmaf(t, hi[1], acc.w);
                ok0 = okn; x0 = xn; b0 = bn;
            }
        }
        // reduce the 4 quarters (lanes l16, l16+16, l16+32, l16+48)
        acc.x += __shfl_xor(acc.x, 16, 64);
        acc.y += __shfl_xor(acc.y, 16, 64);
        acc.z += __shfl_xor(acc.z, 16, 64);
        acc.w += __shfl_xor(acc.w, 16, 64);
        acc.x += __shfl_xor(acc.x, 32, 64);
        acc.y += __shfl_xor(acc.y, 32, 64);
        acc.z += __shfl_xor(acc.z, 32, 64);
        acc.w += __shfl_xor(acc.w, 32, 64);
        float dg = fmaxf((float)cnt, 1.f);
        float nd = rsqrtf(dg);            // norm[n]
        float sd = dg * nd;               // sqrt(deg) = 1/norm
        if (q == 0) {
            // residual from the fp16 row (full precision path)
            __half2 ha = xs2h2[(size_t)n * 32 + l16 * 2];
            __half2 hb = xs2h2[(size_t)n * 32 + l16 * 2 + 1];
            float2 fa = __half22float2(ha);
            float2 fb = __half22float2(hb);
            float4 v;
            v.x = fmaf(0.5f * sd, fa.x, acc.x * nd);
            v.y = fmaf(0.5f * sd, fa.y, acc.y * nd);
            v.z = fmaf(0.5f * sd, fb.x, acc.z * nd);
            v.w = fmaf(0.5f * sd, fb.y, acc.w * nd);
            ((float4*)v_out)[(size_t)n * 16 + l16] = v;
        }
    }
}

// ---------------- gemm2 in-place on d_out: out = v @ W2 + b2 ----------------
__global__ __launch_bounds__(256, 3) void k_gemm2(
    float* __restrict__ v, const float* __restrict__ W2, const float* __restrict__ b2)
{
    __shared__ float Ws[FEAT * OUT_DIM];  // 16 KB
    __shared__ float vT[16 * 260];        // 16.25 KB
    const int tid = threadIdx.x;
    const int r0  = blockIdx.x * 256;

    for (int i = tid; i < FEAT * OUT_DIM / 4; i += 256)
        ((float4*)Ws)[i] = ((const float4*)W2)[i];

    const int rg = tid >> 2;
    const int cg = tid & 3;
    const int c0 = cg * 16;
    float acc[4][16];
#pragma unroll
    for (int i = 0; i < 4; ++i)
#pragma unroll
        for (int j = 0; j < 16; ++j) acc[i][j] = 0.f;

    const int  myrow = r0 + tid;
    const bool rok   = myrow < N_NODES;

    for (int kc = 0; kc < FEAT / 16; ++kc) {
        float4 f[4];
        if (rok) {
            const float4* vp = (const float4*)(v + (size_t)myrow * FEAT + kc * 16);
            f[0] = vp[0]; f[1] = vp[1]; f[2] = vp[2]; f[3] = vp[3];
        } else {
            f[0] = f[1] = f[2] = f[3] = make_float4(0.f, 0.f, 0.f, 0.f);
        }
        __syncthreads();
#pragma unroll
        for (int q = 0; q < 4; ++q) {
            vT[(q * 4 + 0) * 260 + tid] = f[q].x;
            vT[(q * 4 + 1) * 260 + tid] = f[q].y;
            vT[(q * 4 + 2) * 260 + tid] = f[q].z;
            vT[(q * 4 + 3) * 260 + tid] = f[q].w;
        }
        __syncthreads();
#pragma unroll
        for (int kk = 0; kk < 16; ++kk) {
            float4 a4 = *(const float4*)&vT[kk * 260 + rg * 4];
            const float* wrow = &Ws[(kc * 16 + kk) * OUT_DIM + c0];
            float4 w0 = ((const float4*)wrow)[0];
            float4 w1 = ((const float4*)wrow)[1];
            float4 w2 = ((const float4*)wrow)[2];
            float4 w3 = ((const float4*)wrow)[3];
            const float a[4] = {a4.x, a4.y, a4.z, a4.w};
            const float w[16] = {w0.x, w0.y, w0.z, w0.w, w1.x, w1.y, w1.z, w1.w,
                                 w2.x, w2.y, w2.z, w2.w, w3.x, w3.y, w3.z, w3.w};
#pragma unroll
            for (int i = 0; i < 4; ++i)
#pragma unroll
                for (int j = 0; j < 16; ++j)
                    acc[i][j] = fmaf(a[i], w[j], acc[i][j]);
        }
    }

#pragma unroll
    for (int i = 0; i < 4; ++i) {
        int r = r0 + rg * 4 + i;
        if (r >= N_NODES) continue;
        float* op = &v[(size_t)r * OUT_DIM + c0];
#pragma unroll
        for (int q = 0; q < 4; ++q) {
            float4 o = make_float4(acc[i][q*4]   + b2[c0 + q*4],
                                   acc[i][q*4+1] + b2[c0 + q*4 + 1],
                                   acc[i][q*4+2] + b2[c0 + q*4 + 2],
                                   acc[i][q*4+3] + b2[c0 + q*4 + 3]);
            ((float4*)op)[q] = o;
        }
    }
}

extern "C" void kernel_launch(void* const* d_in, const int* in_sizes, int n_in,
                              void* d_out, int out_size, void* d_ws, size_t ws_size,
                              hipStream_t stream)
{
    const float* h   = (const float*)d_in[0];
    const int*   src = (const int*)d_in[1];
    const int*   dst = (const int*)d_in[2];
    const float* W1  = (const float*)d_in[3];
    const float* b1  = (const float*)d_in[4];
    const float* W2  = (const float*)d_in[5];
    const float* b2  = (const float*)d_in[6];
    const float* gW  = (const float*)d_in[7];
    const float* gb  = (const float*)d_in[8];
    float* out = (float*)d_out;

    // ws: bucket_cursor[NBKT] | binned[NBKT*CAP] | src_sorted[E] | rowptr[N+1] | deg[N]
    //     | aproj[N*4] | bproj[N*4] | xs2h[N*64] f16 | xq[N*16] u32 (fp8)
    int* bucket_cursor = (int*)d_ws;
    int* binned        = bucket_cursor + NBKT;
    int* src_sorted    = binned + (size_t)NBKT * CAP;
    int* rowptr        = src_sorted + E_EDGES;
    int* deg           = rowptr + (N_NODES + 1);
    float* aproj       = (float*)(deg + N_NODES);
    float* bproj       = aproj + (size_t)N_NODES * 4;
    __half* xs2h       = (__half*)(bproj + (size_t)N_NODES * 4);
    unsigned int* xq   = (unsigned int*)(xs2h + (size_t)N_NODES * FEAT);

    hipMemsetAsync(bucket_cursor, 0, NBKT * sizeof(int), stream);

    k_binscatter <<<NSCB, 256, 0, stream>>>(src, dst, bucket_cursor, binned);
    k_bucketfinal<<<NBKT, 256, 0, stream>>>(binned, bucket_cursor, deg, rowptr, src_sorted);
    k_gemm1      <<<G1B, 256, 0, stream>>>(h, W1, b1, deg, gW, xs2h, xq, aproj, bproj);
    k_aggregate  <<<2048, 256, 0, stream>>>(xq, (const __half2*)xs2h, aproj, bproj,
                                            rowptr, src_sorted, gb, out);
    k_gemm2      <<<G1B, 256, 0, stream>>>(out, W2, b2);
}